// Round 10
// baseline (410.957 us; speedup 1.0000x reference)
//
#include <hip/hip_runtime.h>
#include <math.h>

#define D 128
#define NNODES 8192
#define NEDGES 16384
#define NSTEMS 4096
#define NGRAPHS 256
#define NSTEPS 12
#define OPS 105
#define SLOPE 0.01f
#define MT 32              // nodes per block
#define NB (NNODES / MT)   // 256 blocks -> 1 block/CU (co-resident by capacity)
#define ECAP 512           // edge-list capacity per block (mean 64)
#define LDA 136            // padded halfs per LDS row (h/m tiles)
#define LDA2 264           // padded halfs per LDS row (stem cat tile)
#define LDQ2 34            // padded floats per Q row (bank-stagger)
#define LDH 132            // padded floats per Hs row

typedef _Float16 half_t;
typedef __attribute__((ext_vector_type(8))) _Float16 f16x8;
typedef __attribute__((ext_vector_type(4))) float f32x4;

__device__ __forceinline__ float leaky(float x) { return x > 0.f ? x : SLOPE * x; }
__device__ __forceinline__ float fast_sigmoid(float x) {
    return __builtin_amdgcn_rcpf(1.f + __expf(-x));
}
__device__ __forceinline__ float fast_tanh(float x) {
    float e = __expf(2.f * x);
    return 1.f - 2.f * __builtin_amdgcn_rcpf(e + 1.f);
}

// Flag-arrival barrier with single-checker detection (zero serialized RMWs).
// bar[0..255]: per-block arrival flags (monotonic sync_no; release store by each leader
// -- contention-free). bar[288]: go word. Block 0's wave 0 polls all 256 flags
// (4 coalesced acquire loads/lane) and publishes go; other leaders poll go only.
// R6's regression was ALL blocks polling ALL flags (65K concurrent loads/round);
// one checker removes the storm while keeping parallel arrivals.
// Visibility: payload (agent-scope stores, drained by syncthreads) -> flag release ->
// checker flag acquire -> go release -> consumer go acquire -> payload loads. Transitive
// release/acquire chain; same protocol class proven R3/R5/R7/R9.
__device__ __forceinline__ void gbar_arrive(int* bar, int sync_no) {
    __syncthreads();   // drains vmcnt -> all agent-scope payload stores visible
    if (threadIdx.x == 0)
        __hip_atomic_store(&bar[blockIdx.x], sync_no, __ATOMIC_RELEASE,
                           __HIP_MEMORY_SCOPE_AGENT);
}
__device__ __forceinline__ void gbar_wait(int* bar, int sync_no) {
    if (blockIdx.x == 0) {
        if (threadIdx.x < 64) {
            const int base = threadIdx.x * 4;
            for (;;) {
                int a = __hip_atomic_load(&bar[base + 0], __ATOMIC_ACQUIRE, __HIP_MEMORY_SCOPE_AGENT);
                int b = __hip_atomic_load(&bar[base + 1], __ATOMIC_ACQUIRE, __HIP_MEMORY_SCOPE_AGENT);
                int c = __hip_atomic_load(&bar[base + 2], __ATOMIC_ACQUIRE, __HIP_MEMORY_SCOPE_AGENT);
                int d = __hip_atomic_load(&bar[base + 3], __ATOMIC_ACQUIRE, __HIP_MEMORY_SCOPE_AGENT);
                int ok = (a >= sync_no) & (b >= sync_no) & (c >= sync_no) & (d >= sync_no);
                if (__all(ok)) break;
                __builtin_amdgcn_s_sleep(1);
            }
            if (threadIdx.x == 0)
                __hip_atomic_store(&bar[288], sync_no, __ATOMIC_RELEASE,
                                   __HIP_MEMORY_SCOPE_AGENT);
        }
        __syncthreads();
    } else {
        if (threadIdx.x == 0) {
            while (__hip_atomic_load(&bar[288], __ATOMIC_ACQUIRE,
                                     __HIP_MEMORY_SCOPE_AGENT) < sync_no)
                __builtin_amdgcn_s_sleep(1);
        }
        __syncthreads();
    }
}

// ---------------- setup: pack weights + transpose g1 + zero barrier words ----------------
// B-frag 16x16x32: lane L supplies B[k = kt*32 + (L>>4)*8 + j][n = nt*16 + (L&15)], j=0..7.
// idx = ((nt*KT + kt)*64 + L)*8 + j
__global__ void k_setup(
    const float* __restrict__ root, const float* __restrict__ wih,
    const float* __restrict__ whh, const float* __restrict__ bond,
    const float* __restrict__ sw1, const float* __restrict__ sw2,
    const float* __restrict__ sw3, const float* __restrict__ bw1,
    const float* __restrict__ bw2, const float* __restrict__ gw1,
    half_t* __restrict__ rootP, half_t* __restrict__ WihP,
    half_t* __restrict__ WhhP, half_t* __restrict__ bondTP,
    half_t* __restrict__ s1P, half_t* __restrict__ s2P, half_t* __restrict__ s3P,
    half_t* __restrict__ w1P, half_t* __restrict__ w2P, half_t* __restrict__ bondQP,
    float* __restrict__ g1T, int* __restrict__ zeroi) {
    int idx = blockIdx.x * 256 + threadIdx.x;
    int which = blockIdx.y;
    if (which == 10) {   // g1T transpose
        if (idx < 128 * 128) {
            int r = idx >> 7, c = idx & 127;
            g1T[c * 128 + r] = gw1[idx];
        }
        return;
    }
    if (which == 11) {   // zero barrier words
        if (idx < 1024) zeroi[idx] = 0;
        return;
    }
    int KT = (which == 4) ? 8 : (which == 9) ? 1 : 4;
    int NT = (which == 1 || which == 2) ? 24 : (which == 3) ? 2 : (which == 6) ? 7 : 8;
    if (idx >= NT * KT * 512) return;
    int j = idx & 7;
    int L = (idx >> 3) & 63;
    int t = idx >> 9;
    int kt = t % KT, nt = t / KT;
    int k = kt * 32 + (L >> 4) * 8 + j;
    int n = nt * 16 + (L & 15);
    switch (which) {
        case 0: rootP[idx] = (half_t)root[k * D + n]; break;
        case 1: WihP[idx] = (half_t)wih[n * D + k]; break;
        case 2: WhhP[idx] = (half_t)whh[n * D + k]; break;
        case 3: bondTP[idx] = (half_t)bond[n * D + k]; break;
        case 4: s1P[idx] = (half_t)sw1[n * 256 + k]; break;
        case 5: s2P[idx] = (half_t)sw2[n * 128 + k]; break;
        case 6: s3P[idx] = (n < OPS) ? (half_t)sw3[n * 128 + k] : (half_t)0.f; break;
        case 7: w1P[idx] = (half_t)bw1[n * D + k]; break;
        case 8: w2P[idx] = (half_t)bw2[n * D + k]; break;
        case 9: bondQP[idx] = (half_t)bond[k * D + n]; break;   // Q@bond: B[k=t][n]
    }
}

__device__ __forceinline__ int lower_bound_dev(const int* a, int n, int v) {
    int lo = 0, hi = n;
    while (lo < hi) {
        int m = (lo + hi) >> 1;
        if (a[m] < v) lo = m + 1;
        else hi = m;
    }
    return lo;
}

// ---------------- fused persistent kernel: edges + init + 12 steps + heads ----------------
// 256 blocks (1/CU) x 512 threads, regular launch (grid <= capacity -> co-resident).
// h in LDS all 12 steps; ALL B-frags (root, gh, gi, agg, bondT) persistent in registers.
// Barrier split: arrive after publishing P; local gh MFMAs between arrive and wait;
// gather-load latency hidden under conv MFMAs; agg A-frag built directly from fp32 Q;
// last wait hidden under the embStem half of the stem-head s1 GEMM.
__global__ __launch_bounds__(512, 2) void k_fused(
    const int* __restrict__ x, const float* __restrict__ embBlock,
    const half_t* __restrict__ w1P, const float* __restrict__ b1i,
    const half_t* __restrict__ w2P, const float* __restrict__ b2i,
    const half_t* __restrict__ rootP, const half_t* __restrict__ WihP,
    const half_t* __restrict__ WhhP, const half_t* __restrict__ bondTP,
    const half_t* __restrict__ bondQP,
    const float* __restrict__ cbias, const float* __restrict__ bih,
    const float* __restrict__ bhh,
    const int* __restrict__ eidx, const int* __restrict__ eattr,
    float* __restrict__ Pbuf0, float* __restrict__ Pbuf1,
    float* __restrict__ hF,
    const int* __restrict__ sni, const int* __restrict__ stypes,
    const float* __restrict__ embStem,
    const half_t* __restrict__ s1P, const float* __restrict__ sb1,
    const half_t* __restrict__ s2P, const float* __restrict__ sb2,
    const half_t* __restrict__ s3P, const float* __restrict__ sb3,
    const int* __restrict__ batch, const float* __restrict__ g1T,
    const float* __restrict__ gb1, const float* __restrict__ gw2,
    const float* __restrict__ gb2, float* __restrict__ dout,
    int* __restrict__ bar) {
    __shared__ __align__(16) half_t As[MT * LDA];
    __shared__ __align__(16) half_t Am[MT * LDA];
    __shared__ __align__(16) float Hs[MT * LDH];
    __shared__ __align__(16) float Q[MT * LDQ2];
    __shared__ __align__(16) int4 elist[ECAP];
    __shared__ int degs_s[MT];
    __shared__ int ecnt;

    const int tid = threadIdx.x;
    const int w = tid >> 6;
    const int lane = tid & 63;
    const int quad = lane >> 4;
    const int l16 = lane & 15;
    const int n0 = blockIdx.x * MT;
    const int c = w * 16 + l16;

    if (tid < MT) degs_s[tid] = 0;
    if (tid == 0) ecnt = 0;
    for (int i = tid; i < MT * LDQ2; i += 512) Q[i] = 0.f;
    __syncthreads();

    // ---- stage embBlock[x] + extract this block's edges (int4 scan) ----
    {
        int row = tid >> 4;
        int col = (tid & 15) * 8;
        const float* src = embBlock + (size_t)x[n0 + row] * D + col;
        float4 v0 = ((const float4*)src)[0];
        float4 v1 = ((const float4*)src)[1];
        f16x8 hv;
        hv[0] = (half_t)v0.x; hv[1] = (half_t)v0.y; hv[2] = (half_t)v0.z; hv[3] = (half_t)v0.w;
        hv[4] = (half_t)v1.x; hv[5] = (half_t)v1.y; hv[6] = (half_t)v1.z; hv[7] = (half_t)v1.w;
        *(f16x8*)&As[row * LDA + col] = hv;
    }
    {
        const int4* dst4 = (const int4*)(eidx + NEDGES);
        for (int e4 = tid; e4 < NEDGES / 4; e4 += 512) {
            int4 dd = dst4[e4];
            int eb = e4 * 4;
            int dv[4] = {dd.x, dd.y, dd.z, dd.w};
#pragma unroll
            for (int q2 = 0; q2 < 4; ++q2) {
                unsigned r = (unsigned)(dv[q2] - n0);
                if (r < MT) {
                    int slot = atomicAdd(&ecnt, 1);
                    atomicAdd(&degs_s[r], 1);
                    if (slot < ECAP) {
                        int e = eb + q2;
                        int2 aa = *(const int2*)(eattr + 2 * e);
                        elist[slot] = make_int4(eidx[e], aa.x, aa.y, (int)r);
                    }
                }
            }
        }
    }
    // ---- persistent B-fragments: root (4), gh (12), gi (12), agg (1), bondT (4) ----
    f16x8 rootB[4], ghB[12], giB[12], aggB, bondTB[4];
#pragma unroll
    for (int kt = 0; kt < 4; ++kt)
        rootB[kt] = *(const f16x8*)(rootP + (size_t)((w * 4 + kt) * 64 + lane) * 8);
#pragma unroll
    for (int kt = 0; kt < 4; ++kt)
#pragma unroll
        for (int g = 0; g < 3; ++g)
            ghB[g * 4 + kt] = *(const f16x8*)(WhhP + (size_t)(((g * 8 + w) * 4 + kt) * 64 + lane) * 8);
#pragma unroll
    for (int kt = 0; kt < 4; ++kt)
#pragma unroll
        for (int g = 0; g < 3; ++g)
            giB[g * 4 + kt] = *(const f16x8*)(WihP + (size_t)(((g * 8 + w) * 4 + kt) * 64 + lane) * 8);
    aggB = *(const f16x8*)(bondQP + (size_t)(w * 64 + lane) * 8);
    {
        const int ntb = w & 1;
#pragma unroll
        for (int kt = 0; kt < 4; ++kt)
            bondTB[kt] = *(const f16x8*)(bondTP + (size_t)((ntb * 4 + kt) * 64 + lane) * 8);
    }
    const float cb = cbias[c];
    const float bi0 = bih[c], bi1 = bih[D + c], bi2 = bih[2 * D + c];
    const float bh0 = bhh[c], bh1 = bhh[D + c], bh2 = bhh[2 * D + c];
    __syncthreads();

    // ---- per-thread edge registers (persist across all steps) ----
    int4 ep = make_int4(0, 0, 0, 0);
    float idg = 0.f;
    const int m = min(ecnt, ECAP);
    const bool have = (tid < m);
    if (have) {
        ep = elist[tid];
        idg = 1.0f / (float)degs_s[ep.w];
    }

    // ---- block2emb MLP layer 1: As -> Am ----
    {
        f32x4 acc[2] = {{0.f, 0.f, 0.f, 0.f}, {0.f, 0.f, 0.f, 0.f}};
#pragma unroll
        for (int kt = 0; kt < 4; ++kt) {
            f16x8 b = *(const f16x8*)(w1P + (size_t)((w * 4 + kt) * 64 + lane) * 8);
            f16x8 a0 = *(const f16x8*)&As[(0 + l16) * LDA + kt * 32 + quad * 8];
            f16x8 a1 = *(const f16x8*)&As[(16 + l16) * LDA + kt * 32 + quad * 8];
            acc[0] = __builtin_amdgcn_mfma_f32_16x16x32_f16(a0, b, acc[0], 0, 0, 0);
            acc[1] = __builtin_amdgcn_mfma_f32_16x16x32_f16(a1, b, acc[1], 0, 0, 0);
        }
        float bb = b1i[c];
#pragma unroll
        for (int mt = 0; mt < 2; ++mt)
#pragma unroll
            for (int r = 0; r < 4; ++r)
                Am[(mt * 16 + quad * 4 + r) * LDA + c] = (half_t)leaky(acc[mt][r] + bb);
    }
    __syncthreads();
    // ---- layer 2: Am -> h (Hs fp32 + As fp16) ----
    {
        f32x4 acc[2] = {{0.f, 0.f, 0.f, 0.f}, {0.f, 0.f, 0.f, 0.f}};
#pragma unroll
        for (int kt = 0; kt < 4; ++kt) {
            f16x8 b = *(const f16x8*)(w2P + (size_t)((w * 4 + kt) * 64 + lane) * 8);
            f16x8 a0 = *(const f16x8*)&Am[(0 + l16) * LDA + kt * 32 + quad * 8];
            f16x8 a1 = *(const f16x8*)&Am[(16 + l16) * LDA + kt * 32 + quad * 8];
            acc[0] = __builtin_amdgcn_mfma_f32_16x16x32_f16(a0, b, acc[0], 0, 0, 0);
            acc[1] = __builtin_amdgcn_mfma_f32_16x16x32_f16(a1, b, acc[1], 0, 0, 0);
        }
        float bb = b2i[c];
#pragma unroll
        for (int mt = 0; mt < 2; ++mt)
#pragma unroll
            for (int r = 0; r < 4; ++r) {
                int row = mt * 16 + quad * 4 + r;
                float h = acc[mt][r] + bb;
                Hs[row * LDH + c] = h;
                As[row * LDA + c] = (half_t)h;
            }
    }
    __syncthreads();
    // ---- P0 = h0 @ bond^T (agent-scope stores -> coherent point) ----
    if (w < 4) {
        int mt = w >> 1;
        f32x4 acc = {0.f, 0.f, 0.f, 0.f};
#pragma unroll
        for (int kt = 0; kt < 4; ++kt) {
            f16x8 a = *(const f16x8*)&As[(mt * 16 + l16) * LDA + kt * 32 + quad * 8];
            acc = __builtin_amdgcn_mfma_f32_16x16x32_f16(a, bondTB[kt], acc, 0, 0, 0);
        }
#pragma unroll
        for (int r = 0; r < 4; ++r)
            __hip_atomic_store(
                &Pbuf0[(size_t)(n0 + mt * 16 + quad * 4 + r) * 32 + (w & 1) * 16 + l16],
                acc[r], __ATOMIC_RELAXED, __HIP_MEMORY_SCOPE_AGENT);
    }
    gbar_arrive(bar, 1);

    float* Pp = Pbuf0;
    float* Pn = Pbuf1;
    for (int step = 0; step < NSTEPS; ++step) {
        // (A) local gh MFMAs -- overlap the barrier wait
        f32x4 ghA[2][3];
#pragma unroll
        for (int mt = 0; mt < 2; ++mt)
#pragma unroll
            for (int g = 0; g < 3; ++g) ghA[mt][g] = f32x4{0.f, 0.f, 0.f, 0.f};
#pragma unroll
        for (int kt = 0; kt < 4; ++kt) {
            f16x8 a0 = *(const f16x8*)&As[(0 + l16) * LDA + kt * 32 + quad * 8];
            f16x8 a1 = *(const f16x8*)&As[(16 + l16) * LDA + kt * 32 + quad * 8];
#pragma unroll
            for (int g = 0; g < 3; ++g) {
                ghA[0][g] = __builtin_amdgcn_mfma_f32_16x16x32_f16(a0, ghB[g * 4 + kt], ghA[0][g], 0, 0, 0);
                ghA[1][g] = __builtin_amdgcn_mfma_f32_16x16x32_f16(a1, ghB[g * 4 + kt], ghA[1][g], 0, 0, 0);
            }
        }
        // (B) wait until all blocks published P(step)
        gbar_wait(bar, step + 1);
        // (C) gather (load latency hidden under conv MFMAs)
        float wv = 0.f;
        if (have)
            wv = __hip_atomic_load(&Pp[(size_t)ep.x * 32 + ep.y],
                                   __ATOMIC_RELAXED, __HIP_MEMORY_SCOPE_AGENT) * idg;
        f32x4 convAcc[2] = {{0.f, 0.f, 0.f, 0.f}, {0.f, 0.f, 0.f, 0.f}};
#pragma unroll
        for (int kt = 0; kt < 4; ++kt) {
            f16x8 a0 = *(const f16x8*)&As[(0 + l16) * LDA + kt * 32 + quad * 8];
            f16x8 a1 = *(const f16x8*)&As[(16 + l16) * LDA + kt * 32 + quad * 8];
            convAcc[0] = __builtin_amdgcn_mfma_f32_16x16x32_f16(a0, rootB[kt], convAcc[0], 0, 0, 0);
            convAcc[1] = __builtin_amdgcn_mfma_f32_16x16x32_f16(a1, rootB[kt], convAcc[1], 0, 0, 0);
        }
        if (have) atomicAdd(&Q[ep.w * LDQ2 + ep.z], wv);
        __syncthreads();   // Q complete

        // (D) agg MFMA direct from fp32 Q + m -> Am
#pragma unroll
        for (int mt = 0; mt < 2; ++mt) {
            const float* qrow = &Q[(mt * 16 + l16) * LDQ2 + quad * 8];
            f16x8 a;
#pragma unroll
            for (int jj = 0; jj < 8; ++jj) a[jj] = (half_t)qrow[jj];
            f32x4 acc = {0.f, 0.f, 0.f, 0.f};
            acc = __builtin_amdgcn_mfma_f32_16x16x32_f16(a, aggB, acc, 0, 0, 0);
#pragma unroll
            for (int r = 0; r < 4; ++r) {
                float mm = convAcc[mt][r] + cb + acc[r];
                Am[(mt * 16 + quad * 4 + r) * LDA + c] = (half_t)leaky(mm);
            }
        }
        __syncthreads();   // Am ready; all Q reads done

        // (E) re-zero Q; gi MFMAs + GRU combine
        if (step < NSTEPS - 1)
            for (int i = tid; i < MT * LDQ2; i += 512) Q[i] = 0.f;
        f32x4 giA[2][3];
#pragma unroll
        for (int mt = 0; mt < 2; ++mt)
#pragma unroll
            for (int g = 0; g < 3; ++g) giA[mt][g] = f32x4{0.f, 0.f, 0.f, 0.f};
#pragma unroll
        for (int kt = 0; kt < 4; ++kt) {
            f16x8 a0 = *(const f16x8*)&Am[(0 + l16) * LDA + kt * 32 + quad * 8];
            f16x8 a1 = *(const f16x8*)&Am[(16 + l16) * LDA + kt * 32 + quad * 8];
#pragma unroll
            for (int g = 0; g < 3; ++g) {
                giA[0][g] = __builtin_amdgcn_mfma_f32_16x16x32_f16(a0, giB[g * 4 + kt], giA[0][g], 0, 0, 0);
                giA[1][g] = __builtin_amdgcn_mfma_f32_16x16x32_f16(a1, giB[g * 4 + kt], giA[1][g], 0, 0, 0);
            }
        }
#pragma unroll
        for (int mt = 0; mt < 2; ++mt) {
#pragma unroll
            for (int r = 0; r < 4; ++r) {
                int row = mt * 16 + quad * 4 + r;
                float rg = fast_sigmoid(giA[mt][0][r] + bi0 + ghA[mt][0][r] + bh0);
                float z = fast_sigmoid(giA[mt][1][r] + bi1 + ghA[mt][1][r] + bh1);
                float nn = fast_tanh(giA[mt][2][r] + bi2 + rg * (ghA[mt][2][r] + bh2));
                float hnew = (1.f - z) * nn + z * Hs[row * LDH + c];
                Hs[row * LDH + c] = hnew;
                As[row * LDA + c] = (half_t)hnew;
            }
        }
        __syncthreads();   // As/Hs updated for all waves

        // (F) publish P(step+1), arrive (wait happens next iteration after local gh)
        if (step < NSTEPS - 1) {
            if (w < 4) {   // Pnext = h @ bond^T
                int mt = w >> 1;
                f32x4 acc = {0.f, 0.f, 0.f, 0.f};
#pragma unroll
                for (int kt = 0; kt < 4; ++kt) {
                    f16x8 a = *(const f16x8*)&As[(mt * 16 + l16) * LDA + kt * 32 + quad * 8];
                    acc = __builtin_amdgcn_mfma_f32_16x16x32_f16(a, bondTB[kt], acc, 0, 0, 0);
                }
#pragma unroll
                for (int r = 0; r < 4; ++r)
                    __hip_atomic_store(
                        &Pn[(size_t)(n0 + mt * 16 + quad * 4 + r) * 32 + (w & 1) * 16 + l16],
                        acc[r], __ATOMIC_RELAXED, __HIP_MEMORY_SCOPE_AGENT);
            }
            gbar_arrive(bar, step + 2);
            float* tsw = Pp; Pp = Pn; Pn = tsw;
        }
    }

    // ---- final h -> global (agent 8B stores) + stage embStem half of cat pre-barrier ----
    half_t* cat = As;                 // 16 x LDA2 = 4224 <= 4352 (As dead after last GRU)
    half_t* t1 = Am;                  // 16 x LDA  = 2176
    half_t* t2 = Am + 16 * LDA;       // second half of Am
    const int s0 = blockIdx.x * 16;
    {
        int row = tid >> 4;
        int col = (tid & 15) * 8;
        const unsigned long long* s8 = (const unsigned long long*)&Hs[row * LDH + col];
        unsigned long long* d8 = (unsigned long long*)(hF + (size_t)(n0 + row) * D + col);
#pragma unroll
        for (int q2 = 0; q2 < 4; ++q2)
            __hip_atomic_store(d8 + q2, s8[q2], __ATOMIC_RELAXED, __HIP_MEMORY_SCOPE_AGENT);
    }
    if (tid < 256) {   // embStem half (cols 128..255) -- no hF dependency
        int row = tid >> 4;
        int col = (tid & 15) * 8;
        const float* src = embStem + (size_t)stypes[s0 + row] * D + col;
        float4 v0 = ((const float4*)src)[0];
        float4 v1 = ((const float4*)src)[1];
        f16x8 hv;
        hv[0] = (half_t)v0.x; hv[1] = (half_t)v0.y; hv[2] = (half_t)v0.z; hv[3] = (half_t)v0.w;
        hv[4] = (half_t)v1.x; hv[5] = (half_t)v1.y; hv[6] = (half_t)v1.z; hv[7] = (half_t)v1.w;
        *(f16x8*)&cat[row * LDA2 + 128 + col] = hv;
    }
    gbar_arrive(bar, NSTEPS + 1);   // internal syncthreads drains hF stores + cat-hi

    // partial s1 over embStem half (kt 4..7) -- hides the final barrier wait
    f32x4 accS = {0.f, 0.f, 0.f, 0.f};
#pragma unroll
    for (int kt = 4; kt < 8; ++kt) {
        f16x8 b = *(const f16x8*)(s1P + (size_t)((w * 8 + kt) * 64 + lane) * 8);
        f16x8 a = *(const f16x8*)&cat[l16 * LDA2 + kt * 32 + quad * 8];
        accS = __builtin_amdgcn_mfma_f32_16x16x32_f16(a, b, accS, 0, 0, 0);
    }
    gbar_wait(bar, NSTEPS + 1);

    // ---- stem head: block b owns stems [16b, 16b+16) ----
    if (tid < 256) {   // hF half (cols 0..127)
        int row = tid >> 4;
        int col = (tid & 15) * 8;
        const float* src = hF + (size_t)sni[s0 + row] * D + col;
        float4 v0 = ((const float4*)src)[0];
        float4 v1 = ((const float4*)src)[1];
        f16x8 hv;
        hv[0] = (half_t)v0.x; hv[1] = (half_t)v0.y; hv[2] = (half_t)v0.z; hv[3] = (half_t)v0.w;
        hv[4] = (half_t)v1.x; hv[5] = (half_t)v1.y; hv[6] = (half_t)v1.z; hv[7] = (half_t)v1.w;
        *(f16x8*)&cat[row * LDA2 + col] = hv;
    }
    __syncthreads();
    {
#pragma unroll
        for (int kt = 0; kt < 4; ++kt) {
            f16x8 b = *(const f16x8*)(s1P + (size_t)((w * 8 + kt) * 64 + lane) * 8);
            f16x8 a = *(const f16x8*)&cat[l16 * LDA2 + kt * 32 + quad * 8];
            accS = __builtin_amdgcn_mfma_f32_16x16x32_f16(a, b, accS, 0, 0, 0);
        }
        float bb = sb1[c];
#pragma unroll
        for (int r = 0; r < 4; ++r)
            t1[(quad * 4 + r) * LDA + c] = (half_t)leaky(accS[r] + bb);
    }
    __syncthreads();
    {
        f32x4 acc = {0.f, 0.f, 0.f, 0.f};
#pragma unroll
        for (int kt = 0; kt < 4; ++kt) {
            f16x8 b = *(const f16x8*)(s2P + (size_t)((w * 4 + kt) * 64 + lane) * 8);
            f16x8 a = *(const f16x8*)&t1[l16 * LDA + kt * 32 + quad * 8];
            acc = __builtin_amdgcn_mfma_f32_16x16x32_f16(a, b, acc, 0, 0, 0);
        }
        float bb = sb2[c];
#pragma unroll
        for (int r = 0; r < 4; ++r)
            t2[(quad * 4 + r) * LDA + c] = (half_t)leaky(acc[r] + bb);
    }
    __syncthreads();
    if (w < 7) {
        f32x4 acc = {0.f, 0.f, 0.f, 0.f};
#pragma unroll
        for (int kt = 0; kt < 4; ++kt) {
            f16x8 b = *(const f16x8*)(s3P + (size_t)((w * 4 + kt) * 64 + lane) * 8);
            f16x8 a = *(const f16x8*)&t2[l16 * LDA + kt * 32 + quad * 8];
            acc = __builtin_amdgcn_mfma_f32_16x16x32_f16(a, b, acc, 0, 0, 0);
        }
        int j = w * 16 + l16;
        if (j < OPS) {
            float bb = sb3[j];
#pragma unroll
            for (int r = 0; r < 4; ++r)
                dout[(size_t)(s0 + quad * 4 + r) * OPS + j] = acc[r] + bb;
        }
    }

    // ---- global head: block b owns graph b; 4-way parallel pooling + dot ----
    {
        const int g = blockIdx.x;
        const int j = tid & 127;
        const int grp = tid >> 7;   // 0..3
        float* part = Q;            // 512
        float* mean_s = Q + 512;    // 128
        float* red = Q + 640;       // 128
        int lo = lower_bound_dev(batch, NNODES, g);
        int hi = lower_bound_dev(batch, NNODES, g + 1);
        float sum = 0.f;
        for (int n = lo + grp; n < hi; n += 4) sum += hF[(size_t)n * D + j];
        part[grp * 128 + j] = sum;
        __syncthreads();
        if (grp == 0) {
            float denom = (hi > lo) ? (float)(hi - lo) : 1.0f;
            mean_s[j] = (part[j] + part[128 + j] + part[256 + j] + part[384 + j]) / denom;
        }
        __syncthreads();
        float a = 0.f;
        for (int i = grp * 32; i < grp * 32 + 32; ++i) a += mean_s[i] * g1T[i * D + j];
        part[grp * 128 + j] = a;
        __syncthreads();
        if (grp == 0) {
            float aa = part[j] + part[128 + j] + part[256 + j] + part[384 + j] + gb1[j];
            red[j] = leaky(aa) * gw2[j];
        }
        __syncthreads();
        for (int off = 64; off > 0; off >>= 1) {
            if (tid < off) red[tid] += red[tid + off];
            __syncthreads();
        }
        if (tid == 0) dout[NSTEMS * OPS + g] = red[0] + gb2[0];
    }
}

// ---------------- launch ----------------
extern "C" void kernel_launch(void* const* d_in, const int* in_sizes, int n_in,
                              void* d_out, int out_size, void* d_ws, size_t ws_size,
                              hipStream_t stream) {
    const int* x = (const int*)d_in[0];
    const int* stypes = (const int*)d_in[1];
    const int* eattr = (const int*)d_in[2];
    const int* eidx = (const int*)d_in[3];
    const int* sni = (const int*)d_in[4];
    const int* batch = (const int*)d_in[5];
    const float* embBlock = (const float*)d_in[6];
    const float* embStem = (const float*)d_in[7];
    const float* embBond = (const float*)d_in[8];
    const float* b2e_w1 = (const float*)d_in[9];
    const float* b2e_b1 = (const float*)d_in[10];
    const float* b2e_w2 = (const float*)d_in[11];
    const float* b2e_b2 = (const float*)d_in[12];
    const float* conv_root = (const float*)d_in[13];
    const float* conv_bias = (const float*)d_in[14];
    const float* gru_w_ih = (const float*)d_in[15];
    const float* gru_w_hh = (const float*)d_in[16];
    const float* gru_b_ih = (const float*)d_in[17];
    const float* gru_b_hh = (const float*)d_in[18];
    const float* s2p_w1 = (const float*)d_in[19];
    const float* s2p_b1 = (const float*)d_in[20];
    const float* s2p_w2 = (const float*)d_in[21];
    const float* s2p_b2 = (const float*)d_in[22];
    const float* s2p_w3 = (const float*)d_in[23];
    const float* s2p_b3 = (const float*)d_in[24];
    const float* g2p_w1 = (const float*)d_in[25];
    const float* g2p_b1 = (const float*)d_in[26];
    const float* g2p_w2 = (const float*)d_in[27];
    const float* g2p_b2 = (const float*)d_in[28];
    float* out_f = (float*)d_out;

    float* W = (float*)d_ws;
    size_t off = 0;
    auto alloc = [&](size_t words) {
        size_t o = off;
        off += (words + 3) & ~(size_t)3;
        return o;
    };
    float* hF = W + alloc(NNODES * D);
    float* P0 = W + alloc(NNODES * 32);
    float* P1 = W + alloc(NNODES * 32);
    half_t* rootP = (half_t*)(W + alloc(16384 / 2));
    half_t* WihP = (half_t*)(W + alloc(49152 / 2));
    half_t* WhhP = (half_t*)(W + alloc(49152 / 2));
    half_t* bondTP = (half_t*)(W + alloc(4096 / 2));
    half_t* s1P = (half_t*)(W + alloc(32768 / 2));
    half_t* s2P = (half_t*)(W + alloc(16384 / 2));
    half_t* s3P = (half_t*)(W + alloc(14336 / 2));
    half_t* w1P = (half_t*)(W + alloc(16384 / 2));
    half_t* w2P = (half_t*)(W + alloc(16384 / 2));
    half_t* bondQP = (half_t*)(W + alloc(4096 / 2));
    float* g1T = W + alloc(128 * 128);
    int* bar = (int*)(W + alloc(1024));   // flags[256] + go word

    k_setup<<<dim3(192, 12), 256, 0, stream>>>(
        conv_root, gru_w_ih, gru_w_hh, embBond, s2p_w1, s2p_w2, s2p_w3,
        b2e_w1, b2e_w2, g2p_w1,
        rootP, WihP, WhhP, bondTP, s1P, s2P, s3P, w1P, w2P, bondQP,
        g1T, bar);

    k_fused<<<NB, 512, 0, stream>>>(
        x, embBlock,
        w1P, b2e_b1, w2P, b2e_b2,
        rootP, WihP, WhhP, bondTP, bondQP,
        conv_bias, gru_b_ih, gru_b_hh,
        eidx, eattr,
        P0, P1, hF,
        sni, stypes, embStem,
        s1P, s2p_b1, s2P, s2p_b2, s3P, s2p_b3,
        batch, g1T, g2p_b1, g2p_w2, g2p_b2,
        out_f, bar);
}

// Round 11
// 226.828 us; speedup vs baseline: 1.8118x; 1.8118x over previous
//
#include <hip/hip_runtime.h>
#include <math.h>

#define D 128
#define NNODES 8192
#define NEDGES 16384
#define NSTEMS 4096
#define NGRAPHS 256
#define NSTEPS 12
#define OPS 105
#define SLOPE 0.01f
#define MT 32              // nodes per block
#define NB (NNODES / MT)   // 256 blocks -> 1 block/CU (co-resident by capacity)
#define ECAP 512           // src-edge-list capacity per block (mean 64)
#define LDA 136            // padded halfs per LDS row (h/m tiles)
#define LDA2 264           // padded halfs per LDS row (stem cat tile)
#define LDQ2 34            // padded floats per Q/P row (bank-stagger)
#define LDH 132            // padded floats per Hs row

typedef _Float16 half_t;
typedef __attribute__((ext_vector_type(8))) _Float16 f16x8;
typedef __attribute__((ext_vector_type(4))) float f32x4;

__device__ __forceinline__ float leaky(float x) { return x > 0.f ? x : SLOPE * x; }
__device__ __forceinline__ float fast_sigmoid(float x) {
    return __builtin_amdgcn_rcpf(1.f + __expf(-x));
}
__device__ __forceinline__ float fast_tanh(float x) {
    float e = __expf(2.f * x);
    return 1.f - 2.f * __builtin_amdgcn_rcpf(e + 1.f);
}

// Two-level 16x16 grid barrier (R9-proven: push-based detection -- the LAST arriver
// completes the chain on its own arrival path). bar[g*32] g=0..15: group counters;
// bar[512]: root; bar[544]: go. Monotonic cumulative. Payload visibility: agent-scope
// stores drained by the __syncthreads inside gbar_arrive before the release RMW.
__device__ __forceinline__ void gbar_arrive(int* bar, int sync_no) {
    __syncthreads();   // drains vmcnt -> all agent-scope payload stores visible
    if (threadIdx.x == 0) {
        int grp = blockIdx.x >> 4;
        int old = __hip_atomic_fetch_add(&bar[grp * 32], 1,
                                         __ATOMIC_RELEASE, __HIP_MEMORY_SCOPE_AGENT);
        if (old == sync_no * 16 - 1) {
            int r = __hip_atomic_fetch_add(&bar[512], 1,
                                           __ATOMIC_RELEASE, __HIP_MEMORY_SCOPE_AGENT);
            if (r == sync_no * 16 - 1)
                __hip_atomic_store(&bar[544], sync_no,
                                   __ATOMIC_RELEASE, __HIP_MEMORY_SCOPE_AGENT);
        }
    }
}
__device__ __forceinline__ void gbar_wait(int* bar, int sync_no) {
    if (threadIdx.x == 0) {
        while (__hip_atomic_load(&bar[544], __ATOMIC_RELAXED,
                                 __HIP_MEMORY_SCOPE_AGENT) < sync_no)
            __builtin_amdgcn_s_sleep(1);
    }
    __syncthreads();
}

// ---------------- setup: pack weights + transpose g1 + zero bar/Qg ----------------
// B-frag 16x16x32: lane L supplies B[k = kt*32 + (L>>4)*8 + j][n = nt*16 + (L&15)], j=0..7.
__global__ void k_setup(
    const float* __restrict__ root, const float* __restrict__ wih,
    const float* __restrict__ whh, const float* __restrict__ bond,
    const float* __restrict__ sw1, const float* __restrict__ sw2,
    const float* __restrict__ sw3, const float* __restrict__ bw1,
    const float* __restrict__ bw2, const float* __restrict__ gw1,
    half_t* __restrict__ rootP, half_t* __restrict__ WihP,
    half_t* __restrict__ WhhP, half_t* __restrict__ bondTP,
    half_t* __restrict__ s1P, half_t* __restrict__ s2P, half_t* __restrict__ s3P,
    half_t* __restrict__ w1P, half_t* __restrict__ w2P, half_t* __restrict__ bondQP,
    float* __restrict__ g1T, int* __restrict__ zeroi, float* __restrict__ Qg) {
    int idx = blockIdx.x * 256 + threadIdx.x;
    int which = blockIdx.y;
    if (which == 10) {   // g1T transpose
        if (idx < 128 * 128) {
            int r = idx >> 7, c = idx & 127;
            g1T[c * 128 + r] = gw1[idx];
        }
        return;
    }
    if (which == 11) {   // zero barrier words
        if (idx < 1024) zeroi[idx] = 0;
        return;
    }
    if (which == 12) {   // zero both Qg buffers
        for (int i = idx; i < 2 * NNODES * 32; i += 192 * 256) Qg[i] = 0.f;
        return;
    }
    int KT = (which == 4) ? 8 : (which == 9) ? 1 : 4;
    int NT = (which == 1 || which == 2) ? 24 : (which == 3) ? 2 : (which == 6) ? 7 : 8;
    if (idx >= NT * KT * 512) return;
    int j = idx & 7;
    int L = (idx >> 3) & 63;
    int t = idx >> 9;
    int kt = t % KT, nt = t / KT;
    int k = kt * 32 + (L >> 4) * 8 + j;
    int n = nt * 16 + (L & 15);
    switch (which) {
        case 0: rootP[idx] = (half_t)root[k * D + n]; break;
        case 1: WihP[idx] = (half_t)wih[n * D + k]; break;
        case 2: WhhP[idx] = (half_t)whh[n * D + k]; break;
        case 3: bondTP[idx] = (half_t)bond[n * D + k]; break;
        case 4: s1P[idx] = (half_t)sw1[n * 256 + k]; break;
        case 5: s2P[idx] = (half_t)sw2[n * 128 + k]; break;
        case 6: s3P[idx] = (n < OPS) ? (half_t)sw3[n * 128 + k] : (half_t)0.f; break;
        case 7: w1P[idx] = (half_t)bw1[n * D + k]; break;
        case 8: w2P[idx] = (half_t)bw2[n * D + k]; break;
        case 9: bondQP[idx] = (half_t)bond[k * D + n]; break;   // Q@bond: B[k=t][n]
    }
}

__device__ __forceinline__ int lower_bound_dev(const int* a, int n, int v) {
    int lo = 0, hi = n;
    while (lo < hi) {
        int m = (lo + hi) >> 1;
        if (a[m] < v) lo = m + 1;
        else hi = m;
    }
    return lo;
}

// ---------------- fused persistent kernel: edges + init + 12 steps + heads ----------------
// 256 blocks (1/CU) x 512 threads, regular launch (grid <= capacity -> co-resident).
// PUSH-BASED aggregation: each block owns edges by SOURCE. After computing its P rows
// in LDS, it pushes wv = P[src][a0]*inv_deg[dst] via global atomicAdd into
// Qg[step&1][dst*32+a1]. After the barrier, consumers read their OWN Qg rows with one
// coalesced 8B load/thread (no random gather, no LDS atomics, no P global buffer).
// Double-buffered Qg, consumer zeroes after read (zero-before-arrive(k) happens-before
// pushes-after-wait(k) -- closed under the proven release/acquire barrier chain).
__global__ __launch_bounds__(512, 2) void k_fused(
    const int* __restrict__ x, const float* __restrict__ embBlock,
    const half_t* __restrict__ w1P, const float* __restrict__ b1i,
    const half_t* __restrict__ w2P, const float* __restrict__ b2i,
    const half_t* __restrict__ rootP, const half_t* __restrict__ WihP,
    const half_t* __restrict__ WhhP, const half_t* __restrict__ bondTP,
    const half_t* __restrict__ bondQP,
    const float* __restrict__ cbias, const float* __restrict__ bih,
    const float* __restrict__ bhh,
    const int* __restrict__ eidx, const int* __restrict__ eattr,
    float* __restrict__ Qg, float* __restrict__ invDegG,
    float* __restrict__ hF,
    const int* __restrict__ sni, const int* __restrict__ stypes,
    const float* __restrict__ embStem,
    const half_t* __restrict__ s1P, const float* __restrict__ sb1,
    const half_t* __restrict__ s2P, const float* __restrict__ sb2,
    const half_t* __restrict__ s3P, const float* __restrict__ sb3,
    const int* __restrict__ batch, const float* __restrict__ g1T,
    const float* __restrict__ gb1, const float* __restrict__ gw2,
    const float* __restrict__ gb2, float* __restrict__ dout,
    int* __restrict__ bar) {
    __shared__ __align__(16) half_t As[MT * LDA];
    __shared__ __align__(16) half_t Am[MT * LDA];
    __shared__ __align__(16) float Hs[MT * LDH];
    __shared__ __align__(16) float QPs[MT * LDQ2];   // Qs (consume) / Ps (publish) time-shared
    __shared__ __align__(16) int4 elist[ECAP];
    __shared__ int degs_s[MT];
    __shared__ int ecnt;

    const int tid = threadIdx.x;
    const int w = tid >> 6;
    const int lane = tid & 63;
    const int quad = lane >> 4;
    const int l16 = lane & 15;
    const int n0 = blockIdx.x * MT;
    const int c = w * 16 + l16;

    if (tid < MT) degs_s[tid] = 0;
    if (tid == 0) ecnt = 0;
    __syncthreads();

    // ---- stage embBlock[x] + edge scan (src-keyed elist + dst-degree count) ----
    {
        int row = tid >> 4;
        int col = (tid & 15) * 8;
        const float* src = embBlock + (size_t)x[n0 + row] * D + col;
        float4 v0 = ((const float4*)src)[0];
        float4 v1 = ((const float4*)src)[1];
        f16x8 hv;
        hv[0] = (half_t)v0.x; hv[1] = (half_t)v0.y; hv[2] = (half_t)v0.z; hv[3] = (half_t)v0.w;
        hv[4] = (half_t)v1.x; hv[5] = (half_t)v1.y; hv[6] = (half_t)v1.z; hv[7] = (half_t)v1.w;
        *(f16x8*)&As[row * LDA + col] = hv;
    }
    {
        const int4* src4p = (const int4*)eidx;
        const int4* dst4p = (const int4*)(eidx + NEDGES);
        for (int e4 = tid; e4 < NEDGES / 4; e4 += 512) {
            int4 ss = src4p[e4];
            int4 dd = dst4p[e4];
            int eb = e4 * 4;
            int sv[4] = {ss.x, ss.y, ss.z, ss.w};
            int dv[4] = {dd.x, dd.y, dd.z, dd.w};
#pragma unroll
            for (int q2 = 0; q2 < 4; ++q2) {
                unsigned rd = (unsigned)(dv[q2] - n0);
                if (rd < MT) atomicAdd(&degs_s[rd], 1);
                unsigned rs = (unsigned)(sv[q2] - n0);
                if (rs < MT) {
                    int slot = atomicAdd(&ecnt, 1);
                    if (slot < ECAP) {
                        int e = eb + q2;
                        int2 aa = *(const int2*)(eattr + 2 * e);
                        elist[slot] = make_int4((int)rs, aa.x, aa.y, dv[q2]);
                    }
                }
            }
        }
    }
    // ---- persistent B-fragments: root (4), gh (12), gi (12), agg (1), bondT (4) ----
    f16x8 rootB[4], ghB[12], giB[12], aggB, bondTB[4];
#pragma unroll
    for (int kt = 0; kt < 4; ++kt)
        rootB[kt] = *(const f16x8*)(rootP + (size_t)((w * 4 + kt) * 64 + lane) * 8);
#pragma unroll
    for (int kt = 0; kt < 4; ++kt)
#pragma unroll
        for (int g = 0; g < 3; ++g)
            ghB[g * 4 + kt] = *(const f16x8*)(WhhP + (size_t)(((g * 8 + w) * 4 + kt) * 64 + lane) * 8);
#pragma unroll
    for (int kt = 0; kt < 4; ++kt)
#pragma unroll
        for (int g = 0; g < 3; ++g)
            giB[g * 4 + kt] = *(const f16x8*)(WihP + (size_t)(((g * 8 + w) * 4 + kt) * 64 + lane) * 8);
    aggB = *(const f16x8*)(bondQP + (size_t)(w * 64 + lane) * 8);
    {
        const int ntb = w & 1;
#pragma unroll
        for (int kt = 0; kt < 4; ++kt)
            bondTB[kt] = *(const f16x8*)(bondTP + (size_t)((ntb * 4 + kt) * 64 + lane) * 8);
    }
    const float cb = cbias[c];
    const float bi0 = bih[c], bi1 = bih[D + c], bi2 = bih[2 * D + c];
    const float bh0 = bhh[c], bh1 = bhh[D + c], bh2 = bhh[2 * D + c];
    __syncthreads();   // degs + elist + As ready

    // ---- publish inv_deg for my nodes, arrive(1) ----
    if (tid < MT) {
        int dg = degs_s[tid];
        __hip_atomic_store(&invDegG[n0 + tid], dg > 0 ? 1.0f / (float)dg : 0.0f,
                           __ATOMIC_RELAXED, __HIP_MEMORY_SCOPE_AGENT);
    }
    // per-thread src-edge registers
    int4 ep = make_int4(0, 0, 0, 0);
    const int m = min(ecnt, ECAP);
    const bool have = (tid < m);
    if (have) ep = elist[tid];
    gbar_arrive(bar, 1);

    // ---- block2emb MLP layer 1: As -> Am  (hides the invDeg wait) ----
    {
        f32x4 acc[2] = {{0.f, 0.f, 0.f, 0.f}, {0.f, 0.f, 0.f, 0.f}};
#pragma unroll
        for (int kt = 0; kt < 4; ++kt) {
            f16x8 b = *(const f16x8*)(w1P + (size_t)((w * 4 + kt) * 64 + lane) * 8);
            f16x8 a0 = *(const f16x8*)&As[(0 + l16) * LDA + kt * 32 + quad * 8];
            f16x8 a1 = *(const f16x8*)&As[(16 + l16) * LDA + kt * 32 + quad * 8];
            acc[0] = __builtin_amdgcn_mfma_f32_16x16x32_f16(a0, b, acc[0], 0, 0, 0);
            acc[1] = __builtin_amdgcn_mfma_f32_16x16x32_f16(a1, b, acc[1], 0, 0, 0);
        }
        float bb = b1i[c];
#pragma unroll
        for (int mt = 0; mt < 2; ++mt)
#pragma unroll
            for (int r = 0; r < 4; ++r)
                Am[(mt * 16 + quad * 4 + r) * LDA + c] = (half_t)leaky(acc[mt][r] + bb);
    }
    __syncthreads();
    // ---- layer 2: Am -> h (Hs fp32 + As fp16) ----
    {
        f32x4 acc[2] = {{0.f, 0.f, 0.f, 0.f}, {0.f, 0.f, 0.f, 0.f}};
#pragma unroll
        for (int kt = 0; kt < 4; ++kt) {
            f16x8 b = *(const f16x8*)(w2P + (size_t)((w * 4 + kt) * 64 + lane) * 8);
            f16x8 a0 = *(const f16x8*)&Am[(0 + l16) * LDA + kt * 32 + quad * 8];
            f16x8 a1 = *(const f16x8*)&Am[(16 + l16) * LDA + kt * 32 + quad * 8];
            acc[0] = __builtin_amdgcn_mfma_f32_16x16x32_f16(a0, b, acc[0], 0, 0, 0);
            acc[1] = __builtin_amdgcn_mfma_f32_16x16x32_f16(a1, b, acc[1], 0, 0, 0);
        }
        float bb = b2i[c];
#pragma unroll
        for (int mt = 0; mt < 2; ++mt)
#pragma unroll
            for (int r = 0; r < 4; ++r) {
                int row = mt * 16 + quad * 4 + r;
                float h = acc[mt][r] + bb;
                Hs[row * LDH + c] = h;
                As[row * LDA + c] = (half_t)h;
            }
    }
    __syncthreads();
    // ---- wait invDeg, load idg, compute P0 rows in LDS, push step-0 messages ----
    gbar_wait(bar, 1);
    float idg = 0.f;
    if (have)
        idg = __hip_atomic_load(&invDegG[ep.w], __ATOMIC_RELAXED, __HIP_MEMORY_SCOPE_AGENT);
    if (w < 4) {
        int mt = w >> 1;
        f32x4 acc = {0.f, 0.f, 0.f, 0.f};
#pragma unroll
        for (int kt = 0; kt < 4; ++kt) {
            f16x8 a = *(const f16x8*)&As[(mt * 16 + l16) * LDA + kt * 32 + quad * 8];
            acc = __builtin_amdgcn_mfma_f32_16x16x32_f16(a, bondTB[kt], acc, 0, 0, 0);
        }
#pragma unroll
        for (int r = 0; r < 4; ++r)
            QPs[(mt * 16 + quad * 4 + r) * LDQ2 + (w & 1) * 16 + l16] = acc[r];
    }
    __syncthreads();   // Ps ready
    if (have)
        atomicAdd(&Qg[(size_t)ep.w * 32 + ep.z], QPs[ep.x * LDQ2 + ep.y] * idg);
    gbar_arrive(bar, 2);

    for (int step = 0; step < NSTEPS; ++step) {
        // (A) local gh MFMAs -- overlap the barrier wait
        f32x4 ghA[2][3];
#pragma unroll
        for (int mt = 0; mt < 2; ++mt)
#pragma unroll
            for (int g = 0; g < 3; ++g) ghA[mt][g] = f32x4{0.f, 0.f, 0.f, 0.f};
#pragma unroll
        for (int kt = 0; kt < 4; ++kt) {
            f16x8 a0 = *(const f16x8*)&As[(0 + l16) * LDA + kt * 32 + quad * 8];
            f16x8 a1 = *(const f16x8*)&As[(16 + l16) * LDA + kt * 32 + quad * 8];
#pragma unroll
            for (int g = 0; g < 3; ++g) {
                ghA[0][g] = __builtin_amdgcn_mfma_f32_16x16x32_f16(a0, ghB[g * 4 + kt], ghA[0][g], 0, 0, 0);
                ghA[1][g] = __builtin_amdgcn_mfma_f32_16x16x32_f16(a1, ghB[g * 4 + kt], ghA[1][g], 0, 0, 0);
            }
        }
        // (B) wait: all pushes for this step landed
        gbar_wait(bar, step + 2);
        // (C) read OWN Qg rows (coalesced 8B agent loads) + conv MFMAs hide the latency
        float* Qc = Qg + (size_t)(step & 1) * (NNODES * 32) + (size_t)n0 * 32;
        unsigned long long qv =
            __hip_atomic_load((unsigned long long*)(Qc + tid * 2),
                              __ATOMIC_RELAXED, __HIP_MEMORY_SCOPE_AGENT);
        f32x4 convAcc[2] = {{0.f, 0.f, 0.f, 0.f}, {0.f, 0.f, 0.f, 0.f}};
#pragma unroll
        for (int kt = 0; kt < 4; ++kt) {
            f16x8 a0 = *(const f16x8*)&As[(0 + l16) * LDA + kt * 32 + quad * 8];
            f16x8 a1 = *(const f16x8*)&As[(16 + l16) * LDA + kt * 32 + quad * 8];
            convAcc[0] = __builtin_amdgcn_mfma_f32_16x16x32_f16(a0, rootB[kt], convAcc[0], 0, 0, 0);
            convAcc[1] = __builtin_amdgcn_mfma_f32_16x16x32_f16(a1, rootB[kt], convAcc[1], 0, 0, 0);
        }
        {
            union { unsigned long long u; float f[2]; } qu;
            qu.u = qv;
            int row = tid >> 4, col = (tid & 15) * 2;
            QPs[row * LDQ2 + col] = qu.f[0];
            QPs[row * LDQ2 + col + 1] = qu.f[1];
            // zero own rows for reuse at step+2 (happens-before pushes via barrier chain)
            __hip_atomic_store((unsigned long long*)(Qc + tid * 2), 0ULL,
                               __ATOMIC_RELAXED, __HIP_MEMORY_SCOPE_AGENT);
        }
        __syncthreads();   // Qs staged

        // (D) agg MFMA from Qs + m -> Am
#pragma unroll
        for (int mt = 0; mt < 2; ++mt) {
            const float* qrow = &QPs[(mt * 16 + l16) * LDQ2 + quad * 8];
            f16x8 a;
#pragma unroll
            for (int jj = 0; jj < 8; ++jj) a[jj] = (half_t)qrow[jj];
            f32x4 acc = {0.f, 0.f, 0.f, 0.f};
            acc = __builtin_amdgcn_mfma_f32_16x16x32_f16(a, aggB, acc, 0, 0, 0);
#pragma unroll
            for (int r = 0; r < 4; ++r) {
                float mm = convAcc[mt][r] + cb + acc[r];
                Am[(mt * 16 + quad * 4 + r) * LDA + c] = (half_t)leaky(mm);
            }
        }
        __syncthreads();   // Am ready; all Qs reads done

        // (E) gi MFMAs + GRU combine
        f32x4 giA[2][3];
#pragma unroll
        for (int mt = 0; mt < 2; ++mt)
#pragma unroll
            for (int g = 0; g < 3; ++g) giA[mt][g] = f32x4{0.f, 0.f, 0.f, 0.f};
#pragma unroll
        for (int kt = 0; kt < 4; ++kt) {
            f16x8 a0 = *(const f16x8*)&Am[(0 + l16) * LDA + kt * 32 + quad * 8];
            f16x8 a1 = *(const f16x8*)&Am[(16 + l16) * LDA + kt * 32 + quad * 8];
#pragma unroll
            for (int g = 0; g < 3; ++g) {
                giA[0][g] = __builtin_amdgcn_mfma_f32_16x16x32_f16(a0, giB[g * 4 + kt], giA[0][g], 0, 0, 0);
                giA[1][g] = __builtin_amdgcn_mfma_f32_16x16x32_f16(a1, giB[g * 4 + kt], giA[1][g], 0, 0, 0);
            }
        }
#pragma unroll
        for (int mt = 0; mt < 2; ++mt) {
#pragma unroll
            for (int r = 0; r < 4; ++r) {
                int row = mt * 16 + quad * 4 + r;
                float rg = fast_sigmoid(giA[mt][0][r] + bi0 + ghA[mt][0][r] + bh0);
                float z = fast_sigmoid(giA[mt][1][r] + bi1 + ghA[mt][1][r] + bh1);
                float nn = fast_tanh(giA[mt][2][r] + bi2 + rg * (ghA[mt][2][r] + bh2));
                float hnew = (1.f - z) * nn + z * Hs[row * LDH + c];
                Hs[row * LDH + c] = hnew;
                As[row * LDA + c] = (half_t)hnew;
            }
        }
        __syncthreads();   // As/Hs updated for all waves

        // (F) compute P rows in LDS, push messages for step+1, arrive
        if (step < NSTEPS - 1) {
            if (w < 4) {
                int mt = w >> 1;
                f32x4 acc = {0.f, 0.f, 0.f, 0.f};
#pragma unroll
                for (int kt = 0; kt < 4; ++kt) {
                    f16x8 a = *(const f16x8*)&As[(mt * 16 + l16) * LDA + kt * 32 + quad * 8];
                    acc = __builtin_amdgcn_mfma_f32_16x16x32_f16(a, bondTB[kt], acc, 0, 0, 0);
                }
#pragma unroll
                for (int r = 0; r < 4; ++r)
                    QPs[(mt * 16 + quad * 4 + r) * LDQ2 + (w & 1) * 16 + l16] = acc[r];
            }
            __syncthreads();   // Ps ready
            if (have)
                atomicAdd(&Qg[(size_t)((step + 1) & 1) * (NNODES * 32) +
                              (size_t)ep.w * 32 + ep.z],
                          QPs[ep.x * LDQ2 + ep.y] * idg);
            gbar_arrive(bar, step + 3);
        }
    }

    // ---- final h -> global (agent 8B stores) + stage embStem half of cat pre-barrier ----
    half_t* cat = As;                 // 16 x LDA2 = 4224 <= 4352 (As dead after last GRU)
    half_t* t1 = Am;                  // 16 x LDA  = 2176
    half_t* t2 = Am + 16 * LDA;       // second half of Am
    const int s0 = blockIdx.x * 16;
    {
        int row = tid >> 4;
        int col = (tid & 15) * 8;
        const unsigned long long* s8 = (const unsigned long long*)&Hs[row * LDH + col];
        unsigned long long* d8 = (unsigned long long*)(hF + (size_t)(n0 + row) * D + col);
#pragma unroll
        for (int q2 = 0; q2 < 4; ++q2)
            __hip_atomic_store(d8 + q2, s8[q2], __ATOMIC_RELAXED, __HIP_MEMORY_SCOPE_AGENT);
    }
    if (tid < 256) {   // embStem half (cols 128..255) -- no hF dependency
        int row = tid >> 4;
        int col = (tid & 15) * 8;
        const float* src = embStem + (size_t)stypes[s0 + row] * D + col;
        float4 v0 = ((const float4*)src)[0];
        float4 v1 = ((const float4*)src)[1];
        f16x8 hv;
        hv[0] = (half_t)v0.x; hv[1] = (half_t)v0.y; hv[2] = (half_t)v0.z; hv[3] = (half_t)v0.w;
        hv[4] = (half_t)v1.x; hv[5] = (half_t)v1.y; hv[6] = (half_t)v1.z; hv[7] = (half_t)v1.w;
        *(f16x8*)&cat[row * LDA2 + 128 + col] = hv;
    }
    gbar_arrive(bar, NSTEPS + 2);   // internal syncthreads drains hF stores + cat-hi

    // partial s1 over embStem half (kt 4..7) -- hides the final barrier wait
    f32x4 accS = {0.f, 0.f, 0.f, 0.f};
#pragma unroll
    for (int kt = 4; kt < 8; ++kt) {
        f16x8 b = *(const f16x8*)(s1P + (size_t)((w * 8 + kt) * 64 + lane) * 8);
        f16x8 a = *(const f16x8*)&cat[l16 * LDA2 + kt * 32 + quad * 8];
        accS = __builtin_amdgcn_mfma_f32_16x16x32_f16(a, b, accS, 0, 0, 0);
    }
    gbar_wait(bar, NSTEPS + 2);

    // ---- stem head: block b owns stems [16b, 16b+16) ----
    if (tid < 256) {   // hF half (cols 0..127)
        int row = tid >> 4;
        int col = (tid & 15) * 8;
        const float* src = hF + (size_t)sni[s0 + row] * D + col;
        float4 v0 = ((const float4*)src)[0];
        float4 v1 = ((const float4*)src)[1];
        f16x8 hv;
        hv[0] = (half_t)v0.x; hv[1] = (half_t)v0.y; hv[2] = (half_t)v0.z; hv[3] = (half_t)v0.w;
        hv[4] = (half_t)v1.x; hv[5] = (half_t)v1.y; hv[6] = (half_t)v1.z; hv[7] = (half_t)v1.w;
        *(f16x8*)&cat[row * LDA2 + col] = hv;
    }
    __syncthreads();
    {
#pragma unroll
        for (int kt = 0; kt < 4; ++kt) {
            f16x8 b = *(const f16x8*)(s1P + (size_t)((w * 8 + kt) * 64 + lane) * 8);
            f16x8 a = *(const f16x8*)&cat[l16 * LDA2 + kt * 32 + quad * 8];
            accS = __builtin_amdgcn_mfma_f32_16x16x32_f16(a, b, accS, 0, 0, 0);
        }
        float bb = sb1[c];
#pragma unroll
        for (int r = 0; r < 4; ++r)
            t1[(quad * 4 + r) * LDA + c] = (half_t)leaky(accS[r] + bb);
    }
    __syncthreads();
    {
        f32x4 acc = {0.f, 0.f, 0.f, 0.f};
#pragma unroll
        for (int kt = 0; kt < 4; ++kt) {
            f16x8 b = *(const f16x8*)(s2P + (size_t)((w * 4 + kt) * 64 + lane) * 8);
            f16x8 a = *(const f16x8*)&t1[l16 * LDA + kt * 32 + quad * 8];
            acc = __builtin_amdgcn_mfma_f32_16x16x32_f16(a, b, acc, 0, 0, 0);
        }
        float bb = sb2[c];
#pragma unroll
        for (int r = 0; r < 4; ++r)
            t2[(quad * 4 + r) * LDA + c] = (half_t)leaky(acc[r] + bb);
    }
    __syncthreads();
    if (w < 7) {
        f32x4 acc = {0.f, 0.f, 0.f, 0.f};
#pragma unroll
        for (int kt = 0; kt < 4; ++kt) {
            f16x8 b = *(const f16x8*)(s3P + (size_t)((w * 4 + kt) * 64 + lane) * 8);
            f16x8 a = *(const f16x8*)&t2[l16 * LDA + kt * 32 + quad * 8];
            acc = __builtin_amdgcn_mfma_f32_16x16x32_f16(a, b, acc, 0, 0, 0);
        }
        int j = w * 16 + l16;
        if (j < OPS) {
            float bb = sb3[j];
#pragma unroll
            for (int r = 0; r < 4; ++r)
                dout[(size_t)(s0 + quad * 4 + r) * OPS + j] = acc[r] + bb;
        }
    }

    // ---- global head: block b owns graph b; 4-way parallel pooling + dot ----
    {
        const int g = blockIdx.x;
        const int j = tid & 127;
        const int grp = tid >> 7;   // 0..3
        float* part = QPs;          // 512
        float* mean_s = QPs + 512;  // 128
        float* red = QPs + 640;     // 128  (QPs has 1088 floats)
        int lo = lower_bound_dev(batch, NNODES, g);
        int hi = lower_bound_dev(batch, NNODES, g + 1);
        float sum = 0.f;
        for (int n = lo + grp; n < hi; n += 4) sum += hF[(size_t)n * D + j];
        part[grp * 128 + j] = sum;
        __syncthreads();
        if (grp == 0) {
            float denom = (hi > lo) ? (float)(hi - lo) : 1.0f;
            mean_s[j] = (part[j] + part[128 + j] + part[256 + j] + part[384 + j]) / denom;
        }
        __syncthreads();
        float a = 0.f;
        for (int i = grp * 32; i < grp * 32 + 32; ++i) a += mean_s[i] * g1T[i * D + j];
        part[grp * 128 + j] = a;
        __syncthreads();
        if (grp == 0) {
            float aa = part[j] + part[128 + j] + part[256 + j] + part[384 + j] + gb1[j];
            red[j] = leaky(aa) * gw2[j];
        }
        __syncthreads();
        for (int off = 64; off > 0; off >>= 1) {
            if (tid < off) red[tid] += red[tid + off];
            __syncthreads();
        }
        if (tid == 0) dout[NSTEMS * OPS + g] = red[0] + gb2[0];
    }
}

// ---------------- launch ----------------
extern "C" void kernel_launch(void* const* d_in, const int* in_sizes, int n_in,
                              void* d_out, int out_size, void* d_ws, size_t ws_size,
                              hipStream_t stream) {
    const int* x = (const int*)d_in[0];
    const int* stypes = (const int*)d_in[1];
    const int* eattr = (const int*)d_in[2];
    const int* eidx = (const int*)d_in[3];
    const int* sni = (const int*)d_in[4];
    const int* batch = (const int*)d_in[5];
    const float* embBlock = (const float*)d_in[6];
    const float* embStem = (const float*)d_in[7];
    const float* embBond = (const float*)d_in[8];
    const float* b2e_w1 = (const float*)d_in[9];
    const float* b2e_b1 = (const float*)d_in[10];
    const float* b2e_w2 = (const float*)d_in[11];
    const float* b2e_b2 = (const float*)d_in[12];
    const float* conv_root = (const float*)d_in[13];
    const float* conv_bias = (const float*)d_in[14];
    const float* gru_w_ih = (const float*)d_in[15];
    const float* gru_w_hh = (const float*)d_in[16];
    const float* gru_b_ih = (const float*)d_in[17];
    const float* gru_b_hh = (const float*)d_in[18];
    const float* s2p_w1 = (const float*)d_in[19];
    const float* s2p_b1 = (const float*)d_in[20];
    const float* s2p_w2 = (const float*)d_in[21];
    const float* s2p_b2 = (const float*)d_in[22];
    const float* s2p_w3 = (const float*)d_in[23];
    const float* s2p_b3 = (const float*)d_in[24];
    const float* g2p_w1 = (const float*)d_in[25];
    const float* g2p_b1 = (const float*)d_in[26];
    const float* g2p_w2 = (const float*)d_in[27];
    const float* g2p_b2 = (const float*)d_in[28];
    float* out_f = (float*)d_out;

    float* W = (float*)d_ws;
    size_t off = 0;
    auto alloc = [&](size_t words) {
        size_t o = off;
        off += (words + 3) & ~(size_t)3;
        return o;
    };
    float* hF = W + alloc(NNODES * D);
    float* Qg = W + alloc(2 * NNODES * 32);      // double-buffered push accumulators
    float* invDegG = W + alloc(NNODES);
    half_t* rootP = (half_t*)(W + alloc(16384 / 2));
    half_t* WihP = (half_t*)(W + alloc(49152 / 2));
    half_t* WhhP = (half_t*)(W + alloc(49152 / 2));
    half_t* bondTP = (half_t*)(W + alloc(4096 / 2));
    half_t* s1P = (half_t*)(W + alloc(32768 / 2));
    half_t* s2P = (half_t*)(W + alloc(16384 / 2));
    half_t* s3P = (half_t*)(W + alloc(14336 / 2));
    half_t* w1P = (half_t*)(W + alloc(16384 / 2));
    half_t* w2P = (half_t*)(W + alloc(16384 / 2));
    half_t* bondQP = (half_t*)(W + alloc(4096 / 2));
    float* g1T = W + alloc(128 * 128);
    int* bar = (int*)(W + alloc(1024));   // 16x16 barrier words

    k_setup<<<dim3(192, 13), 256, 0, stream>>>(
        conv_root, gru_w_ih, gru_w_hh, embBond, s2p_w1, s2p_w2, s2p_w3,
        b2e_w1, b2e_w2, g2p_w1,
        rootP, WihP, WhhP, bondTP, s1P, s2P, s3P, w1P, w2P, bondQP,
        g1T, bar, Qg);

    k_fused<<<NB, 512, 0, stream>>>(
        x, embBlock,
        w1P, b2e_b1, w2P, b2e_b2,
        rootP, WihP, WhhP, bondTP, bondQP,
        conv_bias, gru_b_ih, gru_b_hh,
        eidx, eattr,
        Qg, invDegG, hF,
        sni, stypes, embStem,
        s1P, s2p_b1, s2P, s2p_b2, s3P, s2p_b3,
        batch, g1T, g2p_b1, g2p_w2, g2p_b2,
        out_f, bar);
}

// Round 12
// 219.689 us; speedup vs baseline: 1.8706x; 1.0325x over previous
//
#include <hip/hip_runtime.h>
#include <math.h>

#define D 128
#define NNODES 8192
#define NEDGES 16384
#define NSTEMS 4096
#define NGRAPHS 256
#define NSTEPS 12
#define OPS 105
#define SLOPE 0.01f
#define MT 32              // nodes per block
#define NB (NNODES / MT)   // 256 blocks -> 1 block/CU (co-resident by capacity)
#define ECAP 512           // edge-list capacity per block (mean 64)
#define LDA 136            // padded halfs per LDS row (h/m tiles)
#define LDA2 264           // padded halfs per LDS row (stem cat tile)
#define LDQ2 34            // padded floats per Q row (bank-stagger)
#define LDH 132            // padded floats per Hs row

typedef _Float16 half_t;
typedef __attribute__((ext_vector_type(8))) _Float16 f16x8;
typedef __attribute__((ext_vector_type(4))) float f32x4;

__device__ __forceinline__ float leaky(float x) { return x > 0.f ? x : SLOPE * x; }
__device__ __forceinline__ float fast_sigmoid(float x) {
    return __builtin_amdgcn_rcpf(1.f + __expf(-x));
}
__device__ __forceinline__ float fast_tanh(float x) {
    float e = __expf(2.f * x);
    return 1.f - 2.f * __builtin_amdgcn_rcpf(e + 1.f);
}

// Two-level 16x16 grid barrier (R5-proven protocol, shallower tree), split arrive/wait.
// bar[g*32] g=0..15: group counters (one 128B line each; 16 blocks/group);
// bar[512]: root counter (16 group-finishers); bar[544]: go word. Monotonic cumulative.
// Push-based detection: the LAST arriver completes the chain on its own arrival path.
// Payload visibility: agent-scope stores drained by the __syncthreads inside
// gbar_arrive before the release RMW (proven R3/R5/R7/R9).
__device__ __forceinline__ void gbar_arrive(int* bar, int sync_no) {
    __syncthreads();   // drains vmcnt -> all agent-scope payload stores visible
    if (threadIdx.x == 0) {
        int grp = blockIdx.x >> 4;
        int old = __hip_atomic_fetch_add(&bar[grp * 32], 1,
                                         __ATOMIC_RELEASE, __HIP_MEMORY_SCOPE_AGENT);
        if (old == sync_no * 16 - 1) {
            int r = __hip_atomic_fetch_add(&bar[512], 1,
                                           __ATOMIC_RELEASE, __HIP_MEMORY_SCOPE_AGENT);
            if (r == sync_no * 16 - 1)
                __hip_atomic_store(&bar[544], sync_no,
                                   __ATOMIC_RELEASE, __HIP_MEMORY_SCOPE_AGENT);
        }
    }
}
__device__ __forceinline__ void gbar_wait(int* bar, int sync_no) {
    if (threadIdx.x == 0) {
        while (__hip_atomic_load(&bar[544], __ATOMIC_RELAXED,
                                 __HIP_MEMORY_SCOPE_AGENT) < sync_no)
            __builtin_amdgcn_s_sleep(1);
    }
    __syncthreads();
}

// ---------------- setup: pack weights + transpose g1 + zero barrier words ----------------
// B-frag 16x16x32: lane L supplies B[k = kt*32 + (L>>4)*8 + j][n = nt*16 + (L&15)], j=0..7.
// idx = ((nt*KT + kt)*64 + L)*8 + j
__global__ void k_setup(
    const float* __restrict__ root, const float* __restrict__ wih,
    const float* __restrict__ whh, const float* __restrict__ bond,
    const float* __restrict__ sw1, const float* __restrict__ sw2,
    const float* __restrict__ sw3, const float* __restrict__ bw1,
    const float* __restrict__ bw2, const float* __restrict__ gw1,
    half_t* __restrict__ rootP, half_t* __restrict__ WihP,
    half_t* __restrict__ WhhP, half_t* __restrict__ bondTP,
    half_t* __restrict__ s1P, half_t* __restrict__ s2P, half_t* __restrict__ s3P,
    half_t* __restrict__ w1P, half_t* __restrict__ w2P, half_t* __restrict__ bondQP,
    float* __restrict__ g1T, int* __restrict__ zeroi) {
    int idx = blockIdx.x * 256 + threadIdx.x;
    int which = blockIdx.y;
    if (which == 10) {   // g1T transpose
        if (idx < 128 * 128) {
            int r = idx >> 7, c = idx & 127;
            g1T[c * 128 + r] = gw1[idx];
        }
        return;
    }
    if (which == 11) {   // zero barrier words
        if (idx < 1024) zeroi[idx] = 0;
        return;
    }
    int KT = (which == 4) ? 8 : (which == 9) ? 1 : 4;
    int NT = (which == 1 || which == 2) ? 24 : (which == 3) ? 2 : (which == 6) ? 7 : 8;
    if (idx >= NT * KT * 512) return;
    int j = idx & 7;
    int L = (idx >> 3) & 63;
    int t = idx >> 9;
    int kt = t % KT, nt = t / KT;
    int k = kt * 32 + (L >> 4) * 8 + j;
    int n = nt * 16 + (L & 15);
    switch (which) {
        case 0: rootP[idx] = (half_t)root[k * D + n]; break;
        case 1: WihP[idx] = (half_t)wih[n * D + k]; break;
        case 2: WhhP[idx] = (half_t)whh[n * D + k]; break;
        case 3: bondTP[idx] = (half_t)bond[n * D + k]; break;
        case 4: s1P[idx] = (half_t)sw1[n * 256 + k]; break;
        case 5: s2P[idx] = (half_t)sw2[n * 128 + k]; break;
        case 6: s3P[idx] = (n < OPS) ? (half_t)sw3[n * 128 + k] : (half_t)0.f; break;
        case 7: w1P[idx] = (half_t)bw1[n * D + k]; break;
        case 8: w2P[idx] = (half_t)bw2[n * D + k]; break;
        case 9: bondQP[idx] = (half_t)bond[k * D + n]; break;   // Q@bond: B[k=t][n]
    }
}

__device__ __forceinline__ int lower_bound_dev(const int* a, int n, int v) {
    int lo = 0, hi = n;
    while (lo < hi) {
        int m = (lo + hi) >> 1;
        if (a[m] < v) lo = m + 1;
        else hi = m;
    }
    return lo;
}

// ---------------- fused persistent kernel: edges + init + 12 steps + heads ----------------
// 256 blocks (1/CU) x 512 threads, regular launch (grid <= capacity -> co-resident).
// h in LDS all 12 steps; ALL B-frags (root, gh, gi, agg, bondT) persistent in registers.
// Barrier split: arrive after publishing P; local gh MFMAs between arrive and wait
// (bounded by detection latency -- more filler would delay the last-arriver's own
// critical path); gather-load latency hidden under conv MFMAs; agg A-frag built
// directly from fp32 Q; last wait hidden under the embStem half of the stem-head s1.
__global__ __launch_bounds__(512, 2) void k_fused(
    const int* __restrict__ x, const float* __restrict__ embBlock,
    const half_t* __restrict__ w1P, const float* __restrict__ b1i,
    const half_t* __restrict__ w2P, const float* __restrict__ b2i,
    const half_t* __restrict__ rootP, const half_t* __restrict__ WihP,
    const half_t* __restrict__ WhhP, const half_t* __restrict__ bondTP,
    const half_t* __restrict__ bondQP,
    const float* __restrict__ cbias, const float* __restrict__ bih,
    const float* __restrict__ bhh,
    const int* __restrict__ eidx, const int* __restrict__ eattr,
    float* __restrict__ Pbuf0, float* __restrict__ Pbuf1,
    float* __restrict__ hF,
    const int* __restrict__ sni, const int* __restrict__ stypes,
    const float* __restrict__ embStem,
    const half_t* __restrict__ s1P, const float* __restrict__ sb1,
    const half_t* __restrict__ s2P, const float* __restrict__ sb2,
    const half_t* __restrict__ s3P, const float* __restrict__ sb3,
    const int* __restrict__ batch, const float* __restrict__ g1T,
    const float* __restrict__ gb1, const float* __restrict__ gw2,
    const float* __restrict__ gb2, float* __restrict__ dout,
    int* __restrict__ bar) {
    __shared__ __align__(16) half_t As[MT * LDA];
    __shared__ __align__(16) half_t Am[MT * LDA];
    __shared__ __align__(16) float Hs[MT * LDH];
    __shared__ __align__(16) float Q[MT * LDQ2];
    __shared__ __align__(16) int4 elist[ECAP];
    __shared__ int degs_s[MT];
    __shared__ int ecnt;

    const int tid = threadIdx.x;
    const int w = tid >> 6;
    const int lane = tid & 63;
    const int quad = lane >> 4;
    const int l16 = lane & 15;
    const int n0 = blockIdx.x * MT;
    const int c = w * 16 + l16;

    if (tid < MT) degs_s[tid] = 0;
    if (tid == 0) ecnt = 0;
    for (int i = tid; i < MT * LDQ2; i += 512) Q[i] = 0.f;
    __syncthreads();

    // ---- stage embBlock[x] + extract this block's edges (int4 scan) ----
    {
        int row = tid >> 4;
        int col = (tid & 15) * 8;
        const float* src = embBlock + (size_t)x[n0 + row] * D + col;
        float4 v0 = ((const float4*)src)[0];
        float4 v1 = ((const float4*)src)[1];
        f16x8 hv;
        hv[0] = (half_t)v0.x; hv[1] = (half_t)v0.y; hv[2] = (half_t)v0.z; hv[3] = (half_t)v0.w;
        hv[4] = (half_t)v1.x; hv[5] = (half_t)v1.y; hv[6] = (half_t)v1.z; hv[7] = (half_t)v1.w;
        *(f16x8*)&As[row * LDA + col] = hv;
    }
    {
        const int4* dst4 = (const int4*)(eidx + NEDGES);
        for (int e4 = tid; e4 < NEDGES / 4; e4 += 512) {
            int4 dd = dst4[e4];
            int eb = e4 * 4;
            int dv[4] = {dd.x, dd.y, dd.z, dd.w};
#pragma unroll
            for (int q2 = 0; q2 < 4; ++q2) {
                unsigned r = (unsigned)(dv[q2] - n0);
                if (r < MT) {
                    int slot = atomicAdd(&ecnt, 1);
                    atomicAdd(&degs_s[r], 1);
                    if (slot < ECAP) {
                        int e = eb + q2;
                        int2 aa = *(const int2*)(eattr + 2 * e);
                        elist[slot] = make_int4(eidx[e], aa.x, aa.y, (int)r);
                    }
                }
            }
        }
    }
    // ---- persistent B-fragments: root (4), gh (12), gi (12), agg (1), bondT (4) ----
    f16x8 rootB[4], ghB[12], giB[12], aggB, bondTB[4];
#pragma unroll
    for (int kt = 0; kt < 4; ++kt)
        rootB[kt] = *(const f16x8*)(rootP + (size_t)((w * 4 + kt) * 64 + lane) * 8);
#pragma unroll
    for (int kt = 0; kt < 4; ++kt)
#pragma unroll
        for (int g = 0; g < 3; ++g)
            ghB[g * 4 + kt] = *(const f16x8*)(WhhP + (size_t)(((g * 8 + w) * 4 + kt) * 64 + lane) * 8);
#pragma unroll
    for (int kt = 0; kt < 4; ++kt)
#pragma unroll
        for (int g = 0; g < 3; ++g)
            giB[g * 4 + kt] = *(const f16x8*)(WihP + (size_t)(((g * 8 + w) * 4 + kt) * 64 + lane) * 8);
    aggB = *(const f16x8*)(bondQP + (size_t)(w * 64 + lane) * 8);
    {
        const int ntb = w & 1;
#pragma unroll
        for (int kt = 0; kt < 4; ++kt)
            bondTB[kt] = *(const f16x8*)(bondTP + (size_t)((ntb * 4 + kt) * 64 + lane) * 8);
    }
    const float cb = cbias[c];
    const float bi0 = bih[c], bi1 = bih[D + c], bi2 = bih[2 * D + c];
    const float bh0 = bhh[c], bh1 = bhh[D + c], bh2 = bhh[2 * D + c];
    __syncthreads();

    // ---- per-thread edge registers (persist across all steps) ----
    int4 ep = make_int4(0, 0, 0, 0);
    float idg = 0.f;
    const int m = min(ecnt, ECAP);
    const bool have = (tid < m);
    if (have) {
        ep = elist[tid];
        idg = 1.0f / (float)degs_s[ep.w];
    }

    // ---- block2emb MLP layer 1: As -> Am ----
    {
        f32x4 acc[2] = {{0.f, 0.f, 0.f, 0.f}, {0.f, 0.f, 0.f, 0.f}};
#pragma unroll
        for (int kt = 0; kt < 4; ++kt) {
            f16x8 b = *(const f16x8*)(w1P + (size_t)((w * 4 + kt) * 64 + lane) * 8);
            f16x8 a0 = *(const f16x8*)&As[(0 + l16) * LDA + kt * 32 + quad * 8];
            f16x8 a1 = *(const f16x8*)&As[(16 + l16) * LDA + kt * 32 + quad * 8];
            acc[0] = __builtin_amdgcn_mfma_f32_16x16x32_f16(a0, b, acc[0], 0, 0, 0);
            acc[1] = __builtin_amdgcn_mfma_f32_16x16x32_f16(a1, b, acc[1], 0, 0, 0);
        }
        float bb = b1i[c];
#pragma unroll
        for (int mt = 0; mt < 2; ++mt)
#pragma unroll
            for (int r = 0; r < 4; ++r)
                Am[(mt * 16 + quad * 4 + r) * LDA + c] = (half_t)leaky(acc[mt][r] + bb);
    }
    __syncthreads();
    // ---- layer 2: Am -> h (Hs fp32 + As fp16) ----
    {
        f32x4 acc[2] = {{0.f, 0.f, 0.f, 0.f}, {0.f, 0.f, 0.f, 0.f}};
#pragma unroll
        for (int kt = 0; kt < 4; ++kt) {
            f16x8 b = *(const f16x8*)(w2P + (size_t)((w * 4 + kt) * 64 + lane) * 8);
            f16x8 a0 = *(const f16x8*)&Am[(0 + l16) * LDA + kt * 32 + quad * 8];
            f16x8 a1 = *(const f16x8*)&Am[(16 + l16) * LDA + kt * 32 + quad * 8];
            acc[0] = __builtin_amdgcn_mfma_f32_16x16x32_f16(a0, b, acc[0], 0, 0, 0);
            acc[1] = __builtin_amdgcn_mfma_f32_16x16x32_f16(a1, b, acc[1], 0, 0, 0);
        }
        float bb = b2i[c];
#pragma unroll
        for (int mt = 0; mt < 2; ++mt)
#pragma unroll
            for (int r = 0; r < 4; ++r) {
                int row = mt * 16 + quad * 4 + r;
                float h = acc[mt][r] + bb;
                Hs[row * LDH + c] = h;
                As[row * LDA + c] = (half_t)h;
            }
    }
    __syncthreads();
    // ---- P0 = h0 @ bond^T (agent-scope stores -> coherent point) ----
    if (w < 4) {
        int mt = w >> 1;
        f32x4 acc = {0.f, 0.f, 0.f, 0.f};
#pragma unroll
        for (int kt = 0; kt < 4; ++kt) {
            f16x8 a = *(const f16x8*)&As[(mt * 16 + l16) * LDA + kt * 32 + quad * 8];
            acc = __builtin_amdgcn_mfma_f32_16x16x32_f16(a, bondTB[kt], acc, 0, 0, 0);
        }
#pragma unroll
        for (int r = 0; r < 4; ++r)
            __hip_atomic_store(
                &Pbuf0[(size_t)(n0 + mt * 16 + quad * 4 + r) * 32 + (w & 1) * 16 + l16],
                acc[r], __ATOMIC_RELAXED, __HIP_MEMORY_SCOPE_AGENT);
    }
    gbar_arrive(bar, 1);

    float* Pp = Pbuf0;
    float* Pn = Pbuf1;
    for (int step = 0; step < NSTEPS; ++step) {
        // (A) local gh MFMAs -- overlap the barrier wait
        f32x4 ghA[2][3];
#pragma unroll
        for (int mt = 0; mt < 2; ++mt)
#pragma unroll
            for (int g = 0; g < 3; ++g) ghA[mt][g] = f32x4{0.f, 0.f, 0.f, 0.f};
#pragma unroll
        for (int kt = 0; kt < 4; ++kt) {
            f16x8 a0 = *(const f16x8*)&As[(0 + l16) * LDA + kt * 32 + quad * 8];
            f16x8 a1 = *(const f16x8*)&As[(16 + l16) * LDA + kt * 32 + quad * 8];
#pragma unroll
            for (int g = 0; g < 3; ++g) {
                ghA[0][g] = __builtin_amdgcn_mfma_f32_16x16x32_f16(a0, ghB[g * 4 + kt], ghA[0][g], 0, 0, 0);
                ghA[1][g] = __builtin_amdgcn_mfma_f32_16x16x32_f16(a1, ghB[g * 4 + kt], ghA[1][g], 0, 0, 0);
            }
        }
        // (B) wait until all blocks published P(step)
        gbar_wait(bar, step + 1);
        // (C) gather (load latency hidden under conv MFMAs)
        float wv = 0.f;
        if (have)
            wv = __hip_atomic_load(&Pp[(size_t)ep.x * 32 + ep.y],
                                   __ATOMIC_RELAXED, __HIP_MEMORY_SCOPE_AGENT) * idg;
        f32x4 convAcc[2] = {{0.f, 0.f, 0.f, 0.f}, {0.f, 0.f, 0.f, 0.f}};
#pragma unroll
        for (int kt = 0; kt < 4; ++kt) {
            f16x8 a0 = *(const f16x8*)&As[(0 + l16) * LDA + kt * 32 + quad * 8];
            f16x8 a1 = *(const f16x8*)&As[(16 + l16) * LDA + kt * 32 + quad * 8];
            convAcc[0] = __builtin_amdgcn_mfma_f32_16x16x32_f16(a0, rootB[kt], convAcc[0], 0, 0, 0);
            convAcc[1] = __builtin_amdgcn_mfma_f32_16x16x32_f16(a1, rootB[kt], convAcc[1], 0, 0, 0);
        }
        if (have) atomicAdd(&Q[ep.w * LDQ2 + ep.z], wv);
        __syncthreads();   // Q complete

        // (D) agg MFMA direct from fp32 Q + m -> Am
#pragma unroll
        for (int mt = 0; mt < 2; ++mt) {
            const float* qrow = &Q[(mt * 16 + l16) * LDQ2 + quad * 8];
            f16x8 a;
#pragma unroll
            for (int jj = 0; jj < 8; ++jj) a[jj] = (half_t)qrow[jj];
            f32x4 acc = {0.f, 0.f, 0.f, 0.f};
            acc = __builtin_amdgcn_mfma_f32_16x16x32_f16(a, aggB, acc, 0, 0, 0);
#pragma unroll
            for (int r = 0; r < 4; ++r) {
                float mm = convAcc[mt][r] + cb + acc[r];
                Am[(mt * 16 + quad * 4 + r) * LDA + c] = (half_t)leaky(mm);
            }
        }
        __syncthreads();   // Am ready; all Q reads done

        // (E) re-zero Q; gi MFMAs + GRU combine
        if (step < NSTEPS - 1)
            for (int i = tid; i < MT * LDQ2; i += 512) Q[i] = 0.f;
        f32x4 giA[2][3];
#pragma unroll
        for (int mt = 0; mt < 2; ++mt)
#pragma unroll
            for (int g = 0; g < 3; ++g) giA[mt][g] = f32x4{0.f, 0.f, 0.f, 0.f};
#pragma unroll
        for (int kt = 0; kt < 4; ++kt) {
            f16x8 a0 = *(const f16x8*)&Am[(0 + l16) * LDA + kt * 32 + quad * 8];
            f16x8 a1 = *(const f16x8*)&Am[(16 + l16) * LDA + kt * 32 + quad * 8];
#pragma unroll
            for (int g = 0; g < 3; ++g) {
                giA[0][g] = __builtin_amdgcn_mfma_f32_16x16x32_f16(a0, giB[g * 4 + kt], giA[0][g], 0, 0, 0);
                giA[1][g] = __builtin_amdgcn_mfma_f32_16x16x32_f16(a1, giB[g * 4 + kt], giA[1][g], 0, 0, 0);
            }
        }
#pragma unroll
        for (int mt = 0; mt < 2; ++mt) {
#pragma unroll
            for (int r = 0; r < 4; ++r) {
                int row = mt * 16 + quad * 4 + r;
                float rg = fast_sigmoid(giA[mt][0][r] + bi0 + ghA[mt][0][r] + bh0);
                float z = fast_sigmoid(giA[mt][1][r] + bi1 + ghA[mt][1][r] + bh1);
                float nn = fast_tanh(giA[mt][2][r] + bi2 + rg * (ghA[mt][2][r] + bh2));
                float hnew = (1.f - z) * nn + z * Hs[row * LDH + c];
                Hs[row * LDH + c] = hnew;
                As[row * LDA + c] = (half_t)hnew;
            }
        }
        __syncthreads();   // As/Hs updated for all waves

        // (F) publish P(step+1), arrive (wait happens next iteration after local gh)
        if (step < NSTEPS - 1) {
            if (w < 4) {   // Pnext = h @ bond^T
                int mt = w >> 1;
                f32x4 acc = {0.f, 0.f, 0.f, 0.f};
#pragma unroll
                for (int kt = 0; kt < 4; ++kt) {
                    f16x8 a = *(const f16x8*)&As[(mt * 16 + l16) * LDA + kt * 32 + quad * 8];
                    acc = __builtin_amdgcn_mfma_f32_16x16x32_f16(a, bondTB[kt], acc, 0, 0, 0);
                }
#pragma unroll
                for (int r = 0; r < 4; ++r)
                    __hip_atomic_store(
                        &Pn[(size_t)(n0 + mt * 16 + quad * 4 + r) * 32 + (w & 1) * 16 + l16],
                        acc[r], __ATOMIC_RELAXED, __HIP_MEMORY_SCOPE_AGENT);
            }
            gbar_arrive(bar, step + 2);
            float* tsw = Pp; Pp = Pn; Pn = tsw;
        }
    }

    // ---- final h -> global (agent 8B stores) + stage embStem half of cat pre-barrier ----
    half_t* cat = As;                 // 16 x LDA2 = 4224 <= 4352 (As dead after last GRU)
    half_t* t1 = Am;                  // 16 x LDA  = 2176
    half_t* t2 = Am + 16 * LDA;       // second half of Am
    const int s0 = blockIdx.x * 16;
    {
        int row = tid >> 4;
        int col = (tid & 15) * 8;
        const unsigned long long* s8 = (const unsigned long long*)&Hs[row * LDH + col];
        unsigned long long* d8 = (unsigned long long*)(hF + (size_t)(n0 + row) * D + col);
#pragma unroll
        for (int q2 = 0; q2 < 4; ++q2)
            __hip_atomic_store(d8 + q2, s8[q2], __ATOMIC_RELAXED, __HIP_MEMORY_SCOPE_AGENT);
    }
    if (tid < 256) {   // embStem half (cols 128..255) -- no hF dependency
        int row = tid >> 4;
        int col = (tid & 15) * 8;
        const float* src = embStem + (size_t)stypes[s0 + row] * D + col;
        float4 v0 = ((const float4*)src)[0];
        float4 v1 = ((const float4*)src)[1];
        f16x8 hv;
        hv[0] = (half_t)v0.x; hv[1] = (half_t)v0.y; hv[2] = (half_t)v0.z; hv[3] = (half_t)v0.w;
        hv[4] = (half_t)v1.x; hv[5] = (half_t)v1.y; hv[6] = (half_t)v1.z; hv[7] = (half_t)v1.w;
        *(f16x8*)&cat[row * LDA2 + 128 + col] = hv;
    }
    gbar_arrive(bar, NSTEPS + 1);   // internal syncthreads drains hF stores + cat-hi

    // partial s1 over embStem half (kt 4..7) -- hides the final barrier wait
    f32x4 accS = {0.f, 0.f, 0.f, 0.f};
#pragma unroll
    for (int kt = 4; kt < 8; ++kt) {
        f16x8 b = *(const f16x8*)(s1P + (size_t)((w * 8 + kt) * 64 + lane) * 8);
        f16x8 a = *(const f16x8*)&cat[l16 * LDA2 + kt * 32 + quad * 8];
        accS = __builtin_amdgcn_mfma_f32_16x16x32_f16(a, b, accS, 0, 0, 0);
    }
    gbar_wait(bar, NSTEPS + 1);

    // ---- stem head: block b owns stems [16b, 16b+16) ----
    if (tid < 256) {   // hF half (cols 0..127)
        int row = tid >> 4;
        int col = (tid & 15) * 8;
        const float* src = hF + (size_t)sni[s0 + row] * D + col;
        float4 v0 = ((const float4*)src)[0];
        float4 v1 = ((const float4*)src)[1];
        f16x8 hv;
        hv[0] = (half_t)v0.x; hv[1] = (half_t)v0.y; hv[2] = (half_t)v0.z; hv[3] = (half_t)v0.w;
        hv[4] = (half_t)v1.x; hv[5] = (half_t)v1.y; hv[6] = (half_t)v1.z; hv[7] = (half_t)v1.w;
        *(f16x8*)&cat[row * LDA2 + col] = hv;
    }
    __syncthreads();
    {
#pragma unroll
        for (int kt = 0; kt < 4; ++kt) {
            f16x8 b = *(const f16x8*)(s1P + (size_t)((w * 8 + kt) * 64 + lane) * 8);
            f16x8 a = *(const f16x8*)&cat[l16 * LDA2 + kt * 32 + quad * 8];
            accS = __builtin_amdgcn_mfma_f32_16x16x32_f16(a, b, accS, 0, 0, 0);
        }
        float bb = sb1[c];
#pragma unroll
        for (int r = 0; r < 4; ++r)
            t1[(quad * 4 + r) * LDA + c] = (half_t)leaky(accS[r] + bb);
    }
    __syncthreads();
    {
        f32x4 acc = {0.f, 0.f, 0.f, 0.f};
#pragma unroll
        for (int kt = 0; kt < 4; ++kt) {
            f16x8 b = *(const f16x8*)(s2P + (size_t)((w * 4 + kt) * 64 + lane) * 8);
            f16x8 a = *(const f16x8*)&t1[l16 * LDA + kt * 32 + quad * 8];
            acc = __builtin_amdgcn_mfma_f32_16x16x32_f16(a, b, acc, 0, 0, 0);
        }
        float bb = sb2[c];
#pragma unroll
        for (int r = 0; r < 4; ++r)
            t2[(quad * 4 + r) * LDA + c] = (half_t)leaky(acc[r] + bb);
    }
    __syncthreads();
    if (w < 7) {
        f32x4 acc = {0.f, 0.f, 0.f, 0.f};
#pragma unroll
        for (int kt = 0; kt < 4; ++kt) {
            f16x8 b = *(const f16x8*)(s3P + (size_t)((w * 4 + kt) * 64 + lane) * 8);
            f16x8 a = *(const f16x8*)&t2[l16 * LDA + kt * 32 + quad * 8];
            acc = __builtin_amdgcn_mfma_f32_16x16x32_f16(a, b, acc, 0, 0, 0);
        }
        int j = w * 16 + l16;
        if (j < OPS) {
            float bb = sb3[j];
#pragma unroll
            for (int r = 0; r < 4; ++r)
                dout[(size_t)(s0 + quad * 4 + r) * OPS + j] = acc[r] + bb;
        }
    }

    // ---- global head: block b owns graph b; 4-way parallel pooling + dot ----
    {
        const int g = blockIdx.x;
        const int j = tid & 127;
        const int grp = tid >> 7;   // 0..3
        float* part = Q;            // 512
        float* mean_s = Q + 512;    // 128
        float* red = Q + 640;       // 128
        int lo = lower_bound_dev(batch, NNODES, g);
        int hi = lower_bound_dev(batch, NNODES, g + 1);
        float sum = 0.f;
        for (int n = lo + grp; n < hi; n += 4) sum += hF[(size_t)n * D + j];
        part[grp * 128 + j] = sum;
        __syncthreads();
        if (grp == 0) {
            float denom = (hi > lo) ? (float)(hi - lo) : 1.0f;
            mean_s[j] = (part[j] + part[128 + j] + part[256 + j] + part[384 + j]) / denom;
        }
        __syncthreads();
        float a = 0.f;
        for (int i = grp * 32; i < grp * 32 + 32; ++i) a += mean_s[i] * g1T[i * D + j];
        part[grp * 128 + j] = a;
        __syncthreads();
        if (grp == 0) {
            float aa = part[j] + part[128 + j] + part[256 + j] + part[384 + j] + gb1[j];
            red[j] = leaky(aa) * gw2[j];
        }
        __syncthreads();
        for (int off = 64; off > 0; off >>= 1) {
            if (tid < off) red[tid] += red[tid + off];
            __syncthreads();
        }
        if (tid == 0) dout[NSTEMS * OPS + g] = red[0] + gb2[0];
    }
}

// ---------------- launch ----------------
extern "C" void kernel_launch(void* const* d_in, const int* in_sizes, int n_in,
                              void* d_out, int out_size, void* d_ws, size_t ws_size,
                              hipStream_t stream) {
    const int* x = (const int*)d_in[0];
    const int* stypes = (const int*)d_in[1];
    const int* eattr = (const int*)d_in[2];
    const int* eidx = (const int*)d_in[3];
    const int* sni = (const int*)d_in[4];
    const int* batch = (const int*)d_in[5];
    const float* embBlock = (const float*)d_in[6];
    const float* embStem = (const float*)d_in[7];
    const float* embBond = (const float*)d_in[8];
    const float* b2e_w1 = (const float*)d_in[9];
    const float* b2e_b1 = (const float*)d_in[10];
    const float* b2e_w2 = (const float*)d_in[11];
    const float* b2e_b2 = (const float*)d_in[12];
    const float* conv_root = (const float*)d_in[13];
    const float* conv_bias = (const float*)d_in[14];
    const float* gru_w_ih = (const float*)d_in[15];
    const float* gru_w_hh = (const float*)d_in[16];
    const float* gru_b_ih = (const float*)d_in[17];
    const float* gru_b_hh = (const float*)d_in[18];
    const float* s2p_w1 = (const float*)d_in[19];
    const float* s2p_b1 = (const float*)d_in[20];
    const float* s2p_w2 = (const float*)d_in[21];
    const float* s2p_b2 = (const float*)d_in[22];
    const float* s2p_w3 = (const float*)d_in[23];
    const float* s2p_b3 = (const float*)d_in[24];
    const float* g2p_w1 = (const float*)d_in[25];
    const float* g2p_b1 = (const float*)d_in[26];
    const float* g2p_w2 = (const float*)d_in[27];
    const float* g2p_b2 = (const float*)d_in[28];
    float* out_f = (float*)d_out;

    float* W = (float*)d_ws;
    size_t off = 0;
    auto alloc = [&](size_t words) {
        size_t o = off;
        off += (words + 3) & ~(size_t)3;
        return o;
    };
    float* hF = W + alloc(NNODES * D);
    float* P0 = W + alloc(NNODES * 32);
    float* P1 = W + alloc(NNODES * 32);
    half_t* rootP = (half_t*)(W + alloc(16384 / 2));
    half_t* WihP = (half_t*)(W + alloc(49152 / 2));
    half_t* WhhP = (half_t*)(W + alloc(49152 / 2));
    half_t* bondTP = (half_t*)(W + alloc(4096 / 2));
    half_t* s1P = (half_t*)(W + alloc(32768 / 2));
    half_t* s2P = (half_t*)(W + alloc(16384 / 2));
    half_t* s3P = (half_t*)(W + alloc(14336 / 2));
    half_t* w1P = (half_t*)(W + alloc(16384 / 2));
    half_t* w2P = (half_t*)(W + alloc(16384 / 2));
    half_t* bondQP = (half_t*)(W + alloc(4096 / 2));
    float* g1T = W + alloc(128 * 128);
    int* bar = (int*)(W + alloc(1024));   // 16x16 barrier words

    k_setup<<<dim3(192, 12), 256, 0, stream>>>(
        conv_root, gru_w_ih, gru_w_hh, embBond, s2p_w1, s2p_w2, s2p_w3,
        b2e_w1, b2e_w2, g2p_w1,
        rootP, WihP, WhhP, bondTP, s1P, s2P, s3P, w1P, w2P, bondQP,
        g1T, bar);

    k_fused<<<NB, 512, 0, stream>>>(
        x, embBlock,
        w1P, b2e_b1, w2P, b2e_b2,
        rootP, WihP, WhhP, bondTP, bondQP,
        conv_bias, gru_b_ih, gru_b_hh,
        eidx, eattr,
        P0, P1, hF,
        sni, stypes, embStem,
        s1P, s2p_b1, s2P, s2p_b2, s3P, s2p_b3,
        batch, g1T, g2p_b1, g2p_w2, g2p_b2,
        out_f, bar);
}